// Round 1
// baseline (3459.218 us; speedup 1.0000x reference)
//
#include <hip/hip_runtime.h>
#include <math.h>

// AAModel: equivariant GNN conv block.
// N=100000 nodes, E=60000 edges, NS=48 scalar ch, NV=10 vector ch.
// Pipeline: edge_kernel (geometry + edge MLP) -> conv<1> (fused weight-gen GEMM
// + TP contraction + scatter) -> fin1 (seg-mean + residual) -> conv<2> -> fin2.

constexpr float SQ3f = 1.7320508075688772f;
constexpr float INV1 = 0.14433756729740643f;  // 1/sqrt(48)
constexpr float NAc  = 0.10206207261596575f;  // 1/sqrt(2*48)
constexpr float NBc  = 0.22360679774997896f;  // 1/sqrt(2*10)
constexpr float NB3  = 0.12909944487358055f;  // NBc/sqrt(3)
constexpr float C20  = 0.22360679774997896f;  // 1/sqrt(20)
constexpr float DSP  = 30.0f/31.0f;           // GaussianSmearing spacing
constexpr float GCOEF= -0.5f/(DSP*DSP);

// ----------------------------------------------------------------------------
// Edge kernel: one wave per edge. Computes sh1, Gaussian smearing, edge MLP,
// and degree counts.
// ----------------------------------------------------------------------------
__global__ __launch_bounds__(256)
void edge_kernel(const float* __restrict__ pos, const float* __restrict__ sigma,
                 const int* __restrict__ ei,
                 const float* __restrict__ W1, const float* __restrict__ b1,
                 const float* __restrict__ W2, const float* __restrict__ b2,
                 float* __restrict__ edge_emb, float* __restrict__ sh1buf,
                 int* __restrict__ deg, int E)
{
    __shared__ float inl[4][64];
    __shared__ float hidl[4][48];
    const int w    = threadIdx.x >> 6;
    const int lane = threadIdx.x & 63;
    const int e    = blockIdx.x*4 + w;
    const bool valid = (e < E);
    const int ec = valid ? e : 0;
    const int src = ei[ec], dst = ei[E+ec];
    const float vx = pos[dst*3+0]-pos[src*3+0];
    const float vy = pos[dst*3+1]-pos[src*3+1];
    const float vz = pos[dst*3+2]-pos[src*3+2];
    const float d  = sqrtf(vx*vx+vy*vy+vz*vz);
    const float si = SQ3f/(d+1e-8f);
    const float s0 = vx*si, s1 = vy*si, s2 = vz*si;
    if (lane < 32) {
        inl[w][lane] = sigma[src*32+lane];
    } else {
        const float off  = (float)(lane-32)*DSP;
        const float diff = d - off;
        inl[w][lane] = expf(GCOEF*diff*diff);
    }
    __syncthreads();
    if (lane < 48) {
        float a = b1[lane];
        #pragma unroll 8
        for (int j=0;j<64;j++) a = fmaf(inl[w][j], W1[j*48+lane], a);
        hidl[w][lane] = fmaxf(a, 0.f);
    }
    __syncthreads();
    if (valid) {
        if (lane < 48) {
            float a = b2[lane];
            #pragma unroll 8
            for (int j=0;j<48;j++) a = fmaf(hidl[w][j], W2[j*48+lane], a);
            edge_emb[e*48+lane] = a;
        }
        if (lane == 0) atomicAdd(&deg[dst], 1);
        if (lane < 3)  sh1buf[e*4+lane] = (lane==0)?s0:((lane==1)?s1:s2);
    }
}

// ----------------------------------------------------------------------------
// Fused conv layer: 32 edges/block, 256 threads.
//  phase A: stage ea^T [144][40] in LDS (+ per-edge xv/u/cross for layer 2)
//  phase B: hidT = relu(ea @ W1 + b1), stored transposed [144][40]
//  main:    per 256-col tile, GEMM hid @ W2 in registers (4e x 8c / thread),
//           epilogue decodes each column -> TP path, LDS-atomic accumulate
//  writeback: per-edge results -> global atomics on node accumulators
// ----------------------------------------------------------------------------
template<int LAYER>
__global__ __launch_bounds__(256, 2)
void conv_kernel(const float* __restrict__ edge_emb, const float* __restrict__ sh1buf,
                 const int* __restrict__ ei,
                 const float* __restrict__ sin_, const float* __restrict__ vin,
                 const float* __restrict__ W1, const float* __restrict__ b1,
                 const float* __restrict__ W2, const float* __restrict__ b2,
                 float* __restrict__ outS, float* __restrict__ outV, int E)
{
    constexpr int NCOL = (LAYER==1) ? 2784 : 3464;
    constexpr int NT   = (NCOL + 255)/256;

    __shared__ __align__(16) float eaT[144][40];
    __shared__ __align__(16) float hidT[144][40];
    __shared__ float accS[32][48];
    __shared__ float accVc[32][10];
    __shared__ float sh1l[32][4];
    __shared__ int   srcl[32], dstl[32];
    __shared__ float xvL[32][30];
    __shared__ float uL[32][10];
    __shared__ float cvL[32][30];
    __shared__ float accV[32][30];
    __shared__ float accP[32][30];

    const int t  = threadIdx.x;
    const int eb = blockIdx.x * 32;

    if (t < 32) {
        const int ge = eb + t; const int gc = (ge < E) ? ge : (E-1);
        srcl[t] = ei[gc]; dstl[t] = ei[E+gc];
    }
    if (t < 128) {
        const int e = t >> 2, k = t & 3;
        const int ge = eb + e; const int gc = (ge<E)?ge:(E-1);
        sh1l[e][k] = sh1buf[gc*4 + k];
    }
    for (int p=t; p<1536; p+=256) (&accS[0][0])[p] = 0.f;
    for (int p=t; p<320;  p+=256) (&accVc[0][0])[p] = 0.f;
    if (LAYER==2) {
        for (int p=t; p<960; p+=256) { (&accV[0][0])[p]=0.f; (&accP[0][0])[p]=0.f; }
    }
    __syncthreads();

    // phase A
    #pragma unroll
    for (int i=0;i<6;i++) {
        const int p = t + 256*i;
        const int e = p/48, o = p - e*48;
        const int ge = eb + e; const int gc = (ge<E)?ge:(E-1);
        eaT[o][e]    = edge_emb[gc*48 + o];
        eaT[48+o][e] = sin_[srcl[e]*48 + o];
        eaT[96+o][e] = sin_[dstl[e]*48 + o];
    }
    if (LAYER==2) {
        for (int p=t; p<320; p+=256) {
            const int e = p/10, i = p - e*10;
            const float* vp = &vin[srcl[e]*30 + i*3];
            const float x0=vp[0], x1=vp[1], x2=vp[2];
            const float h0=sh1l[e][0], h1=sh1l[e][1], h2=sh1l[e][2];
            xvL[e][i*3+0]=x0; xvL[e][i*3+1]=x1; xvL[e][i*3+2]=x2;
            uL[e][i] = x0*h0 + x1*h1 + x2*h2;
            cvL[e][i*3+0] = x1*h2 - x2*h1;
            cvL[e][i*3+1] = x2*h0 - x0*h2;
            cvL[e][i*3+2] = x0*h1 - x1*h0;
        }
    }
    __syncthreads();

    const int te = t >> 5;   // 0..7 : owns edges te*4 .. te*4+3
    const int tc = t & 31;   // 0..31: owns 8 consecutive columns

    // phase B: hidden layer GEMM (N=144 fits one col tile; tc<18 active)
    {
        float acc[4][8] = {};
        if (tc < 18) {
            for (int k=0;k<144;k++) {
                const float4 av = *(const float4*)&eaT[k][te*4];
                const float* wr = &W1[k*144 + tc*8];
                const float4 w0 = *(const float4*)wr;
                const float4 w1 = *(const float4*)(wr+4);
                const float av4[4] = {av.x, av.y, av.z, av.w};
                const float wc[8]  = {w0.x,w0.y,w0.z,w0.w, w1.x,w1.y,w1.z,w1.w};
                #pragma unroll
                for (int ee=0;ee<4;ee++)
                    #pragma unroll
                    for (int cc=0;cc<8;cc++)
                        acc[ee][cc] = fmaf(av4[ee], wc[cc], acc[ee][cc]);
            }
            #pragma unroll
            for (int cc=0;cc<8;cc++) {
                const int c = tc*8 + cc;
                const float bb = b1[c];
                float4 hv;
                hv.x = fmaxf(acc[0][cc]+bb, 0.f);
                hv.y = fmaxf(acc[1][cc]+bb, 0.f);
                hv.z = fmaxf(acc[2][cc]+bb, 0.f);
                hv.w = fmaxf(acc[3][cc]+bb, 0.f);
                *(float4*)&hidT[c][te*4] = hv;
            }
        }
    }
    __syncthreads();

    // main GEMM + fused tensor-product epilogue
    for (int ct=0; ct<NT; ct++) {
        const int c0 = ct*256 + tc*8;
        if (c0 >= NCOL) continue;
        float acc[4][8] = {};
        if (c0 + 8 <= NCOL) {
            for (int k=0;k<144;k++) {
                const float4 av = *(const float4*)&hidT[k][te*4];
                const float* wr = &W2[k*NCOL + c0];
                const float4 w0 = *(const float4*)wr;
                const float4 w1 = *(const float4*)(wr+4);
                const float av4[4] = {av.x, av.y, av.z, av.w};
                const float wc[8]  = {w0.x,w0.y,w0.z,w0.w, w1.x,w1.y,w1.z,w1.w};
                #pragma unroll
                for (int ee=0;ee<4;ee++)
                    #pragma unroll
                    for (int cc=0;cc<8;cc++)
                        acc[ee][cc] = fmaf(av4[ee], wc[cc], acc[ee][cc]);
            }
        } else {
            const int nv = NCOL - c0;
            for (int k=0;k<144;k++) {
                const float4 av = *(const float4*)&hidT[k][te*4];
                const float av4[4] = {av.x, av.y, av.z, av.w};
                #pragma unroll
                for (int cc=0;cc<8;cc++) {
                    const float wv = (cc < nv) ? W2[k*NCOL + c0 + cc] : 0.f;
                    #pragma unroll
                    for (int ee=0;ee<4;ee++)
                        acc[ee][cc] = fmaf(av4[ee], wv, acc[ee][cc]);
                }
            }
        }
        #pragma unroll
        for (int cc=0;cc<8;cc++) {
            const int c = c0 + cc;
            if (c >= NCOL) break;
            const float bb = b2[c];
            if (LAYER==1) {
                if (c < 2304) {                       // 0e(x)0e->0e
                    const int i = c/48, o = c - i*48;
                    #pragma unroll
                    for (int ee=0;ee<4;ee++) {
                        const int e = te*4+ee;
                        atomicAdd(&accS[e][o], (acc[ee][cc]+bb) * eaT[48+i][e]);
                    }
                } else {                              // 0e(x)1o->1o (coef)
                    const int t2 = c - 2304;
                    const int i = t2/10, o = t2 - i*10;
                    #pragma unroll
                    for (int ee=0;ee<4;ee++) {
                        const int e = te*4+ee;
                        atomicAdd(&accVc[e][o], (acc[ee][cc]+bb) * eaT[48+i][e]);
                    }
                }
            } else {
                if (c < 2304) {                       // 0e(x)0e->0e
                    const int i = c/48, o = c - i*48;
                    #pragma unroll
                    for (int ee=0;ee<4;ee++) {
                        const int e = te*4+ee;
                        atomicAdd(&accS[e][o], NAc*(acc[ee][cc]+bb)*eaT[48+i][e]);
                    }
                } else if (c < 2784) {                // 0e(x)1o->1o (coef)
                    const int t2=c-2304; const int i=t2/10, o=t2-i*10;
                    #pragma unroll
                    for (int ee=0;ee<4;ee++) {
                        const int e = te*4+ee;
                        atomicAdd(&accVc[e][o], (acc[ee][cc]+bb)*eaT[48+i][e]);
                    }
                } else if (c < 2884) {                // 1o(x)0e->1o
                    const int t2=c-2784; const int i=t2/10, o=t2-i*10;
                    #pragma unroll
                    for (int ee=0;ee<4;ee++) {
                        const int e = te*4+ee;
                        const float wv = acc[ee][cc]+bb;
                        #pragma unroll
                        for (int d=0; d<3; d++)
                            atomicAdd(&accV[e][o*3+d], wv*xvL[e][i*3+d]);
                    }
                } else if (c < 3364) {                // 1o(x)1o->0e
                    const int t2=c-2884; const int i=t2/48, o=t2-i*48;
                    #pragma unroll
                    for (int ee=0;ee<4;ee++) {
                        const int e = te*4+ee;
                        atomicAdd(&accS[e][o], NB3*(acc[ee][cc]+bb)*uL[e][i]);
                    }
                } else {                              // 1o(x)1o->1e (cross)
                    const int t2=c-3364; const int i=t2/10, o=t2-i*10;
                    #pragma unroll
                    for (int ee=0;ee<4;ee++) {
                        const int e = te*4+ee;
                        const float wv = acc[ee][cc]+bb;
                        #pragma unroll
                        for (int d=0; d<3; d++)
                            atomicAdd(&accP[e][o*3+d], wv*cvL[e][i*3+d]);
                    }
                }
            }
        }
    }
    __syncthreads();

    // writeback: per-edge message -> global node accumulators
    if (LAYER==1) {
        for (int p=t; p<1536; p+=256) {
            const int e=p/48, o=p-(p/48)*48;
            if (eb+e < E) atomicAdd(&outS[dstl[e]*48+o], accS[e][o]*INV1);
        }
        for (int p=t; p<320; p+=256) {
            const int e=p/10, o=p-(p/10)*10;
            if (eb+e < E) {
                const float val = accVc[e][o]*INV1;
                #pragma unroll
                for (int d=0; d<3; d++)
                    atomicAdd(&outV[dstl[e]*30 + o*3 + d], val*sh1l[e][d]);
            }
        }
    } else {
        for (int p=t; p<1536; p+=256) {
            const int e=p/48, o=p-(p/48)*48;
            if (eb+e < E) atomicAdd(&outS[dstl[e]*108 + o], accS[e][o]);
        }
        for (int p=t; p<320; p+=256) {
            const int e=p/10, o=p-(p/10)*10;
            if (eb+e < E) {
                const int base = dstl[e]*108;
                #pragma unroll
                for (int d=0; d<3; d++) {
                    atomicAdd(&outS[base + 48 + o*3 + d],
                              accVc[e][o]*NAc*sh1l[e][d] + accV[e][o*3+d]*NBc);
                    atomicAdd(&outS[base + 78 + o*3 + d], accP[e][o*3+d]*C20);
                }
            }
        }
    }
}

// ----------------------------------------------------------------------------
// Finalize kernels: seg-mean divide + residual adds.
// ----------------------------------------------------------------------------
__global__ __launch_bounds__(256)
void fin1_kernel(const float* __restrict__ node_s, const int* __restrict__ deg,
                 float* __restrict__ s1, float* __restrict__ v1, int Nn)
{
    const int p = blockIdx.x*256 + threadIdx.x;
    const int totS = Nn*48;
    if (p < totS) {
        const int n = p/48;
        const int dgi = deg[n];
        const float dg = (float)(dgi > 1 ? dgi : 1);
        s1[p] = node_s[p] + s1[p]/dg;
    } else {
        const int q = p - totS;
        if (q < Nn*30) {
            const int n = q/30;
            const int dgi = deg[n];
            const float dg = (float)(dgi > 1 ? dgi : 1);
            v1[q] = v1[q]/dg;
        }
    }
}

__global__ __launch_bounds__(256)
void fin2_kernel(const float* __restrict__ s1, const float* __restrict__ v1,
                 const int* __restrict__ deg, float* __restrict__ out, int Nn)
{
    const int p = blockIdx.x*256 + threadIdx.x;
    if (p >= Nn*108) return;
    const int n = p/108, c = p - n*108;
    const int dgi = deg[n];
    const float dg = (float)(dgi > 1 ? dgi : 1);
    const float acc = out[p]/dg;
    if (c < 48)      out[p] = s1[n*48+c] + acc;
    else if (c < 78) out[p] = v1[n*30 + (c-48)] + acc;
    else             out[p] = acc;
}

// ----------------------------------------------------------------------------
extern "C" void kernel_launch(void* const* d_in, const int* in_sizes, int n_in,
                              void* d_out, int out_size, void* d_ws, size_t ws_size,
                              hipStream_t stream)
{
    const float* pos    = (const float*)d_in[0];
    const float* sigma  = (const float*)d_in[1];
    const float* node_s = (const float*)d_in[2];
    const float* eW1  = (const float*)d_in[3];
    const float* eb1  = (const float*)d_in[4];
    const float* eW2  = (const float*)d_in[5];
    const float* eb2  = (const float*)d_in[6];
    const float* f1W1 = (const float*)d_in[7];
    const float* f1b1 = (const float*)d_in[8];
    const float* f1W2 = (const float*)d_in[9];
    const float* f1b2 = (const float*)d_in[10];
    const float* f2W1 = (const float*)d_in[11];
    const float* f2b1 = (const float*)d_in[12];
    const float* f2W2 = (const float*)d_in[13];
    const float* f2b2 = (const float*)d_in[14];
    const int*   ei   = (const int*)d_in[15];
    const int Nn = in_sizes[0]/3;
    const int E  = in_sizes[15]/2;
    float* out = (float*)d_out;

    char* ws = (char*)d_ws;
    float* edge_emb = (float*)ws;  ws += (size_t)E*48*sizeof(float);   // 11.5 MB
    float* sh1buf   = (float*)ws;  ws += (size_t)E*4*sizeof(float);    // 0.96 MB
    float* s1       = (float*)ws;  ws += (size_t)Nn*48*sizeof(float);  // 19.2 MB
    float* v1       = (float*)ws;  ws += (size_t)Nn*30*sizeof(float);  // 12 MB
    int*   deg      = (int*)ws;    ws += (size_t)Nn*sizeof(int);       // 0.4 MB

    hipMemsetAsync(s1,  0, (size_t)Nn*48*sizeof(float), stream);
    hipMemsetAsync(v1,  0, (size_t)Nn*30*sizeof(float), stream);
    hipMemsetAsync(deg, 0, (size_t)Nn*sizeof(int),      stream);
    hipMemsetAsync(out, 0, (size_t)Nn*108*sizeof(float), stream);

    edge_kernel<<<(E+3)/4, 256, 0, stream>>>(pos, sigma, ei, eW1, eb1, eW2, eb2,
                                             edge_emb, sh1buf, deg, E);
    conv_kernel<1><<<(E+31)/32, 256, 0, stream>>>(edge_emb, sh1buf, ei, node_s, nullptr,
                                                  f1W1, f1b1, f1W2, f1b2, s1, v1, E);
    fin1_kernel<<<((size_t)Nn*78 + 255)/256, 256, 0, stream>>>(node_s, deg, s1, v1, Nn);
    conv_kernel<2><<<(E+31)/32, 256, 0, stream>>>(edge_emb, sh1buf, ei, s1, v1,
                                                  f2W1, f2b1, f2W2, f2b2, out, nullptr, E);
    fin2_kernel<<<((size_t)Nn*108 + 255)/256, 256, 0, stream>>>(s1, v1, deg, out, Nn);
}

// Round 2
// 2417.626 us; speedup vs baseline: 1.4308x; 1.4308x over previous
//
#include <hip/hip_runtime.h>
#include <math.h>

// AAModel: equivariant GNN conv block — round 2: bf16 MFMA weight-gen GEMMs.
// Pipeline: edge_kernel -> cvt_swz(W1,W2 layer1) -> conv<1> -> fin1
//           -> cvt_swz(W1,W2 layer2) -> conv<2> -> fin2

constexpr float SQ3f = 1.7320508075688772f;
constexpr float INV1 = 0.14433756729740643f;  // 1/sqrt(48)
constexpr float NAc  = 0.10206207261596575f;  // 1/sqrt(2*48)
constexpr float NBc  = 0.22360679774997896f;  // 1/sqrt(2*10)
constexpr float NB3  = 0.12909944487358055f;  // NBc/sqrt(3)
constexpr float C20  = 0.22360679774997896f;  // 1/sqrt(20)
constexpr float DSP  = 30.0f/31.0f;
constexpr float GCOEF= -0.5f/(DSP*DSP);

typedef __attribute__((ext_vector_type(8))) short bf16x8;
typedef __attribute__((ext_vector_type(4))) float f32x4;

__device__ __forceinline__ unsigned short f2bf(float x) {
    unsigned u = __builtin_bit_cast(unsigned, x);
    u += 0x7fffu + ((u >> 16) & 1u);     // RNE
    return (unsigned short)(u >> 16);
}

// ----------------------------------------------------------------------------
// Weight pre-swizzle: fp32 W[K=144][ncol] -> bf16 B-fragments for
// mfma_f32_16x16x32_bf16. Fragment (tile,ks,lane): n=tile*16+(lane&15),
// k=ks*32+(lane>>4)*8+j.  K padded to 160, n padded to ntile*16, zeros.
// ----------------------------------------------------------------------------
__global__ __launch_bounds__(256)
void cvt_swz(const float* __restrict__ W, short* __restrict__ Wsw,
             int ncol, int ntile)
{
    const int gid = blockIdx.x*256 + threadIdx.x;
    const int g = gid >> 6, lane = gid & 63;
    if (g >= ntile*5) return;
    const int tile = g/5, ks = g - tile*5;
    const int n  = tile*16 + (lane & 15);
    const int k0 = ks*32 + (lane >> 4)*8;
    union { uint4 u4; unsigned short h[8]; } pk;
    #pragma unroll
    for (int j=0;j<8;j++) {
        const int k = k0 + j;
        const float v = (k < 144 && n < ncol) ? W[(size_t)k*ncol + n] : 0.f;
        pk.h[j] = f2bf(v);
    }
    *(uint4*)&Wsw[((size_t)g*64 + lane)*8] = pk.u4;
}

// ----------------------------------------------------------------------------
// Edge kernel (unchanged from round 1)
// ----------------------------------------------------------------------------
__global__ __launch_bounds__(256)
void edge_kernel(const float* __restrict__ pos, const float* __restrict__ sigma,
                 const int* __restrict__ ei,
                 const float* __restrict__ W1, const float* __restrict__ b1,
                 const float* __restrict__ W2, const float* __restrict__ b2,
                 float* __restrict__ edge_emb, float* __restrict__ sh1buf,
                 int* __restrict__ deg, int E)
{
    __shared__ float inl[4][64];
    __shared__ float hidl[4][48];
    const int w    = threadIdx.x >> 6;
    const int lane = threadIdx.x & 63;
    const int e    = blockIdx.x*4 + w;
    const bool valid = (e < E);
    const int ec = valid ? e : 0;
    const int src = ei[ec], dst = ei[E+ec];
    const float vx = pos[dst*3+0]-pos[src*3+0];
    const float vy = pos[dst*3+1]-pos[src*3+1];
    const float vz = pos[dst*3+2]-pos[src*3+2];
    const float d  = sqrtf(vx*vx+vy*vy+vz*vz);
    const float si = SQ3f/(d+1e-8f);
    const float s0 = vx*si, s1 = vy*si, s2 = vz*si;
    if (lane < 32) {
        inl[w][lane] = sigma[src*32+lane];
    } else {
        const float off  = (float)(lane-32)*DSP;
        const float diff = d - off;
        inl[w][lane] = expf(GCOEF*diff*diff);
    }
    __syncthreads();
    if (lane < 48) {
        float a = b1[lane];
        #pragma unroll 8
        for (int j=0;j<64;j++) a = fmaf(inl[w][j], W1[j*48+lane], a);
        hidl[w][lane] = fmaxf(a, 0.f);
    }
    __syncthreads();
    if (valid) {
        if (lane < 48) {
            float a = b2[lane];
            #pragma unroll 8
            for (int j=0;j<48;j++) a = fmaf(hidl[w][j], W2[j*48+lane], a);
            edge_emb[e*48+lane] = a;
        }
        if (lane == 0) atomicAdd(&deg[dst], 1);
        if (lane < 3)  sh1buf[e*4+lane] = (lane==0)?s0:((lane==1)?s1:s2);
    }
}

// ----------------------------------------------------------------------------
// Fused MFMA conv layer: 32 edges/block, 256 threads (4 waves).
// ----------------------------------------------------------------------------
template<int LAYER>
__global__ __launch_bounds__(256, 2)
void conv_kernel(const float* __restrict__ edge_emb, const float* __restrict__ sh1buf,
                 const int* __restrict__ ei,
                 const float* __restrict__ sin_, const float* __restrict__ vin,
                 const short* __restrict__ W1sw, const float* __restrict__ b1,
                 const short* __restrict__ W2sw, const float* __restrict__ b2,
                 float* __restrict__ outS, float* __restrict__ outV, int E)
{
    constexpr int NCOL = (LAYER==1) ? 2784 : 3464;
    constexpr int NT16 = (NCOL + 15)/16;     // 174 / 217

    __shared__ short eaB[32*192];            // bf16, XOR-swizzled (16B slots)
    __shared__ short hidB[32*192];
    __shared__ float xsL[32*48];
    __shared__ float accS[32*50];
    __shared__ float accVc[32*10];
    __shared__ float sh1l[32][4];
    __shared__ int   srcl[32], dstl[32];
    __shared__ float xvL [LAYER==2 ? 32*30 : 1];
    __shared__ float uL  [LAYER==2 ? 32*10 : 1];
    __shared__ float cvL [LAYER==2 ? 32*30 : 1];
    __shared__ float accV[LAYER==2 ? 32*30 : 1];
    __shared__ float accP[LAYER==2 ? 32*30 : 1];

    const int t  = threadIdx.x;
    const int eb = blockIdx.x * 32;

    if (t < 32) {
        const int ge = eb + t; const int gc = (ge < E) ? ge : (E-1);
        srcl[t] = ei[gc]; dstl[t] = ei[E+gc];
    }
    if (t < 128) {
        const int e = t >> 2, k = t & 3;
        const int ge = eb + e; const int gc = (ge<E)?ge:(E-1);
        sh1l[e][k] = sh1buf[gc*4 + k];
    }
    for (int p=t; p<1600; p+=256) accS[p] = 0.f;
    for (int p=t; p<320;  p+=256) accVc[p] = 0.f;
    if (LAYER==2)
        for (int p=t; p<960; p+=256) { accV[p]=0.f; accP[p]=0.f; }
    __syncthreads();

    // ---- phase A: stage ea as bf16 into swizzled LDS (+ fp32 epilogue copies)
    for (int p = t; p < 32*24; p += 256) {
        const int m = p / 24, s = p - m*24;
        const int k0 = s*8;
        float vals[8];
        if (k0 < 48) {
            const int ge = eb + m; const int gc = (ge<E)?ge:(E-1);
            const float4 a = *(const float4*)&edge_emb[gc*48 + k0];
            const float4 b = *(const float4*)&edge_emb[gc*48 + k0 + 4];
            vals[0]=a.x; vals[1]=a.y; vals[2]=a.z; vals[3]=a.w;
            vals[4]=b.x; vals[5]=b.y; vals[6]=b.z; vals[7]=b.w;
        } else if (k0 < 96) {
            const float4 a = *(const float4*)&sin_[srcl[m]*48 + (k0-48)];
            const float4 b = *(const float4*)&sin_[srcl[m]*48 + (k0-48) + 4];
            vals[0]=a.x; vals[1]=a.y; vals[2]=a.z; vals[3]=a.w;
            vals[4]=b.x; vals[5]=b.y; vals[6]=b.z; vals[7]=b.w;
            #pragma unroll
            for (int j=0;j<8;j++) xsL[m*48 + (k0-48) + j] = vals[j];
        } else if (k0 < 144) {
            const float4 a = *(const float4*)&sin_[dstl[m]*48 + (k0-96)];
            const float4 b = *(const float4*)&sin_[dstl[m]*48 + (k0-96) + 4];
            vals[0]=a.x; vals[1]=a.y; vals[2]=a.z; vals[3]=a.w;
            vals[4]=b.x; vals[5]=b.y; vals[6]=b.z; vals[7]=b.w;
        } else {
            #pragma unroll
            for (int j=0;j<8;j++) vals[j] = 0.f;
        }
        union { uint4 u4; unsigned short h[8]; } pk;
        #pragma unroll
        for (int j=0;j<8;j++) pk.h[j] = f2bf(vals[j]);
        *(uint4*)&eaB[m*192 + ((s ^ (m&7))*8)] = pk.u4;
    }
    // zero hidB K-pad slots (k=144..191) so MFMA sees 0 (not NaN garbage)
    for (int p = t; p < 32*6; p += 256) {
        const int m = p/6, s = 18 + (p - (p/6)*6);
        uint4 z; z.x=z.y=z.z=z.w=0u;
        *(uint4*)&hidB[m*192 + ((s ^ (m&7))*8)] = z;
    }
    if (LAYER==2) {
        for (int p=t; p<320; p+=256) {
            const int e = p/10, i = p - e*10;
            const float* vp = &vin[srcl[e]*30 + i*3];
            const float x0=vp[0], x1=vp[1], x2=vp[2];
            const float h0=sh1l[e][0], h1=sh1l[e][1], h2=sh1l[e][2];
            xvL[e*30+i*3+0]=x0; xvL[e*30+i*3+1]=x1; xvL[e*30+i*3+2]=x2;
            uL[e*10+i] = x0*h0 + x1*h1 + x2*h2;
            cvL[e*30+i*3+0] = x1*h2 - x2*h1;
            cvL[e*30+i*3+1] = x2*h0 - x0*h2;
            cvL[e*30+i*3+2] = x0*h1 - x1*h0;
        }
    }
    __syncthreads();

    const int wv = t >> 6, lane = t & 63;
    const int lm = lane & 15, lk = lane >> 4;

    // ---- GEMM1: hid = relu(ea @ W1 + b1), MFMA, output -> swizzled bf16 LDS
    {
        bf16x8 af[2][5];
        #pragma unroll
        for (int mt=0; mt<2; mt++) {
            const int m = mt*16 + lm;
            #pragma unroll
            for (int ks=0; ks<5; ks++)
                af[mt][ks] = *(const bf16x8*)&eaB[m*192 + (((ks*4+lk) ^ (m&7))*8)];
        }
        for (int nt = wv; nt < 9; nt += 4) {
            bf16x8 bf_[5];
            #pragma unroll
            for (int ks=0; ks<5; ks++)
                bf_[ks] = *(const bf16x8*)&W1sw[((size_t)(nt*5+ks)*64 + lane)*8];
            f32x4 acc[2];
            acc[0] = (f32x4){0.f,0.f,0.f,0.f};
            acc[1] = (f32x4){0.f,0.f,0.f,0.f};
            #pragma unroll
            for (int ks=0; ks<5; ks++) {
                acc[0] = __builtin_amdgcn_mfma_f32_16x16x32_bf16(af[0][ks], bf_[ks], acc[0], 0,0,0);
                acc[1] = __builtin_amdgcn_mfma_f32_16x16x32_bf16(af[1][ks], bf_[ks], acc[1], 0,0,0);
            }
            const int c  = nt*16 + lm;
            const float bb = b1[c];
            #pragma unroll
            for (int mt=0; mt<2; mt++)
                #pragma unroll
                for (int reg=0; reg<4; reg++) {
                    const int m = mt*16 + lk*4 + reg;
                    const float v = fmaxf(acc[mt][reg] + bb, 0.f);
                    hidB[m*192 + (((c>>3) ^ (m&7))*8) + (c&7)] = (short)f2bf(v);
                }
        }
    }
    __syncthreads();

    // ---- GEMM2 + fused TP epilogue
    {
        bf16x8 ag[2][5];
        #pragma unroll
        for (int mt=0; mt<2; mt++) {
            const int m = mt*16 + lm;
            #pragma unroll
            for (int ks=0; ks<5; ks++)
                ag[mt][ks] = *(const bf16x8*)&hidB[m*192 + (((ks*4+lk) ^ (m&7))*8)];
        }
        bf16x8 bc[5];
        if (wv < NT16) {
            #pragma unroll
            for (int ks=0; ks<5; ks++)
                bc[ks] = *(const bf16x8*)&W2sw[((size_t)(wv*5+ks)*64 + lane)*8];
        }
        for (int ct = wv; ct < NT16; ct += 4) {
            bf16x8 bn[5];
            const int ctn = ct + 4;
            if (ctn < NT16) {
                #pragma unroll
                for (int ks=0; ks<5; ks++)
                    bn[ks] = *(const bf16x8*)&W2sw[((size_t)(ctn*5+ks)*64 + lane)*8];
            }
            f32x4 acc[2];
            acc[0] = (f32x4){0.f,0.f,0.f,0.f};
            acc[1] = (f32x4){0.f,0.f,0.f,0.f};
            #pragma unroll
            for (int ks=0; ks<5; ks++) {
                acc[0] = __builtin_amdgcn_mfma_f32_16x16x32_bf16(ag[0][ks], bc[ks], acc[0], 0,0,0);
                acc[1] = __builtin_amdgcn_mfma_f32_16x16x32_bf16(ag[1][ks], bc[ks], acc[1], 0,0,0);
            }
            const int c = ct*16 + lm;
            if (c < NCOL) {
                const float bb = b2[c];
                if (LAYER==1) {
                    int i, o, tgt;
                    if (c < 2304) { i = c/48; o = c - i*48; tgt = 0; }
                    else { const int t2 = c-2304; i = t2/10; o = t2 - i*10; tgt = 1; }
                    #pragma unroll
                    for (int mt=0; mt<2; mt++)
                        #pragma unroll
                        for (int reg=0; reg<4; reg++) {
                            const int e = mt*16 + lk*4 + reg;
                            const float v = (acc[mt][reg] + bb) * xsL[e*48 + i];
                            if (tgt==0) atomicAdd(&accS[e*50 + o], v);
                            else        atomicAdd(&accVc[e*10 + o], v);
                        }
                } else {
                    if (c < 2304) {
                        const int i = c/48, o = c - (c/48)*48;
                        #pragma unroll
                        for (int mt=0; mt<2; mt++)
                            #pragma unroll
                            for (int reg=0; reg<4; reg++) {
                                const int e = mt*16 + lk*4 + reg;
                                atomicAdd(&accS[e*50 + o],
                                          NAc*(acc[mt][reg] + bb)*xsL[e*48 + i]);
                            }
                    } else if (c < 2784) {
                        const int t2=c-2304; const int i=t2/10, o=t2-i*10;
                        #pragma unroll
                        for (int mt=0; mt<2; mt++)
                            #pragma unroll
                            for (int reg=0; reg<4; reg++) {
                                const int e = mt*16 + lk*4 + reg;
                                atomicAdd(&accVc[e*10 + o],
                                          (acc[mt][reg] + bb)*xsL[e*48 + i]);
                            }
                    } else if (c < 2884) {
                        const int t2=c-2784; const int i=t2/10, o=t2-i*10;
                        #pragma unroll
                        for (int mt=0; mt<2; mt++)
                            #pragma unroll
                            for (int reg=0; reg<4; reg++) {
                                const int e = mt*16 + lk*4 + reg;
                                const float v = acc[mt][reg] + bb;
                                #pragma unroll
                                for (int d=0; d<3; d++)
                                    atomicAdd(&accV[e*30 + o*3 + d], v*xvL[e*30 + i*3 + d]);
                            }
                    } else if (c < 3364) {
                        const int t2=c-2884; const int i=t2/48, o=t2-i*48;
                        #pragma unroll
                        for (int mt=0; mt<2; mt++)
                            #pragma unroll
                            for (int reg=0; reg<4; reg++) {
                                const int e = mt*16 + lk*4 + reg;
                                atomicAdd(&accS[e*50 + o],
                                          NB3*(acc[mt][reg] + bb)*uL[e*10 + i]);
                            }
                    } else {
                        const int t2=c-3364; const int i=t2/10, o=t2-i*10;
                        #pragma unroll
                        for (int mt=0; mt<2; mt++)
                            #pragma unroll
                            for (int reg=0; reg<4; reg++) {
                                const int e = mt*16 + lk*4 + reg;
                                const float v = acc[mt][reg] + bb;
                                #pragma unroll
                                for (int d=0; d<3; d++)
                                    atomicAdd(&accP[e*30 + o*3 + d], v*cvL[e*30 + i*3 + d]);
                            }
                    }
                }
            }
            #pragma unroll
            for (int ks=0; ks<5; ks++) bc[ks] = bn[ks];
        }
    }
    __syncthreads();

    // ---- writeback
    if (LAYER==1) {
        for (int p=t; p<1536; p+=256) {
            const int e=p/48, o=p-(p/48)*48;
            if (eb+e < E) atomicAdd(&outS[dstl[e]*48+o], accS[e*50+o]*INV1);
        }
        for (int p=t; p<320; p+=256) {
            const int e=p/10, o=p-(p/10)*10;
            if (eb+e < E) {
                const float val = accVc[e*10+o]*INV1;
                #pragma unroll
                for (int d=0; d<3; d++)
                    atomicAdd(&outV[dstl[e]*30 + o*3 + d], val*sh1l[e][d]);
            }
        }
    } else {
        for (int p=t; p<1536; p+=256) {
            const int e=p/48, o=p-(p/48)*48;
            if (eb+e < E) atomicAdd(&outS[dstl[e]*108 + o], accS[e*50+o]);
        }
        for (int p=t; p<320; p+=256) {
            const int e=p/10, o=p-(p/10)*10;
            if (eb+e < E) {
                const int base = dstl[e]*108;
                #pragma unroll
                for (int d=0; d<3; d++) {
                    atomicAdd(&outS[base + 48 + o*3 + d],
                              accVc[e*10+o]*NAc*sh1l[e][d] + accV[e*30+o*3+d]*NBc);
                    atomicAdd(&outS[base + 78 + o*3 + d], accP[e*30+o*3+d]*C20);
                }
            }
        }
    }
}

// ----------------------------------------------------------------------------
__global__ __launch_bounds__(256)
void fin1_kernel(const float* __restrict__ node_s, const int* __restrict__ deg,
                 float* __restrict__ s1, float* __restrict__ v1, int Nn)
{
    const int p = blockIdx.x*256 + threadIdx.x;
    const int totS = Nn*48;
    if (p < totS) {
        const int n = p/48;
        const int dgi = deg[n];
        const float dg = (float)(dgi > 1 ? dgi : 1);
        s1[p] = node_s[p] + s1[p]/dg;
    } else {
        const int q = p - totS;
        if (q < Nn*30) {
            const int n = q/30;
            const int dgi = deg[n];
            const float dg = (float)(dgi > 1 ? dgi : 1);
            v1[q] = v1[q]/dg;
        }
    }
}

__global__ __launch_bounds__(256)
void fin2_kernel(const float* __restrict__ s1, const float* __restrict__ v1,
                 const int* __restrict__ deg, float* __restrict__ out, int Nn)
{
    const int p = blockIdx.x*256 + threadIdx.x;
    if (p >= Nn*108) return;
    const int n = p/108, c = p - n*108;
    const int dgi = deg[n];
    const float dg = (float)(dgi > 1 ? dgi : 1);
    const float acc = out[p]/dg;
    if (c < 48)      out[p] = s1[n*48+c] + acc;
    else if (c < 78) out[p] = v1[n*30 + (c-48)] + acc;
    else             out[p] = acc;
}

// ----------------------------------------------------------------------------
extern "C" void kernel_launch(void* const* d_in, const int* in_sizes, int n_in,
                              void* d_out, int out_size, void* d_ws, size_t ws_size,
                              hipStream_t stream)
{
    const float* pos    = (const float*)d_in[0];
    const float* sigma  = (const float*)d_in[1];
    const float* node_s = (const float*)d_in[2];
    const float* eW1  = (const float*)d_in[3];
    const float* eb1  = (const float*)d_in[4];
    const float* eW2  = (const float*)d_in[5];
    const float* eb2  = (const float*)d_in[6];
    const float* f1W1 = (const float*)d_in[7];
    const float* f1b1 = (const float*)d_in[8];
    const float* f1W2 = (const float*)d_in[9];
    const float* f1b2 = (const float*)d_in[10];
    const float* f2W1 = (const float*)d_in[11];
    const float* f2b1 = (const float*)d_in[12];
    const float* f2W2 = (const float*)d_in[13];
    const float* f2b2 = (const float*)d_in[14];
    const int*   ei   = (const int*)d_in[15];
    const int Nn = in_sizes[0]/3;
    const int E  = in_sizes[15]/2;
    float* out = (float*)d_out;

    char* ws = (char*)d_ws;
    float* edge_emb = (float*)ws;  ws += (size_t)E*48*sizeof(float);
    float* sh1buf   = (float*)ws;  ws += (size_t)E*4*sizeof(float);
    float* s1       = (float*)ws;  ws += (size_t)Nn*48*sizeof(float);
    float* v1       = (float*)ws;  ws += (size_t)Nn*30*sizeof(float);
    int*   deg      = (int*)ws;    ws += (size_t)Nn*sizeof(int);
    short* W1sw     = (short*)ws;  ws += (size_t)9*5*64*8*sizeof(short);    // 46 KB
    short* W2sw     = (short*)ws;  ws += (size_t)217*5*64*8*sizeof(short);  // 1.11 MB

    hipMemsetAsync(s1,  0, (size_t)Nn*48*sizeof(float), stream);
    hipMemsetAsync(v1,  0, (size_t)Nn*30*sizeof(float), stream);
    hipMemsetAsync(deg, 0, (size_t)Nn*sizeof(int),      stream);
    hipMemsetAsync(out, 0, (size_t)Nn*108*sizeof(float), stream);

    edge_kernel<<<(E+3)/4, 256, 0, stream>>>(pos, sigma, ei, eW1, eb1, eW2, eb2,
                                             edge_emb, sh1buf, deg, E);

    // layer-1 weights -> bf16 fragments
    cvt_swz<<<(9*5*64+255)/256, 256, 0, stream>>>(f1W1, W1sw, 144, 9);
    cvt_swz<<<(174*5*64+255)/256, 256, 0, stream>>>(f1W2, W2sw, 2784, 174);

    conv_kernel<1><<<(E+31)/32, 256, 0, stream>>>(edge_emb, sh1buf, ei, node_s, nullptr,
                                                  W1sw, f1b1, W2sw, f1b2, s1, v1, E);
    fin1_kernel<<<((size_t)Nn*78 + 255)/256, 256, 0, stream>>>(node_s, deg, s1, v1, Nn);

    // layer-2 weights -> bf16 fragments (reuse buffers; stream-ordered after conv1)
    cvt_swz<<<(9*5*64+255)/256, 256, 0, stream>>>(f2W1, W1sw, 144, 9);
    cvt_swz<<<(217*5*64+255)/256, 256, 0, stream>>>(f2W2, W2sw, 3464, 217);

    conv_kernel<2><<<(E+31)/32, 256, 0, stream>>>(edge_emb, sh1buf, ei, s1, v1,
                                                  W1sw, f2b1, W2sw, f2b2, out, nullptr, E);
    fin2_kernel<<<((size_t)Nn*108 + 255)/256, 256, 0, stream>>>(s1, v1, deg, out, Nn);
}

// Round 3
// 428.601 us; speedup vs baseline: 8.0710x; 5.6407x over previous
//
#include <hip/hip_runtime.h>
#include <math.h>

// AAModel round 3: atomic-free conv epilogue.
// Key idea: permute W2 columns in the pre-swizzle so each MFMA tile has a
// UNIFORM tensor-product input index i; the contraction over i then lives in
// per-lane REGISTERS across the tile loop. Per-wave partials -> private LDS
// (plain writes) -> one cross-wave reduce -> native global f32 atomics
// (unsafeAtomicAdd) for the node scatter. Bias folded in as K-row 144.

constexpr float SQ3f = 1.7320508075688772f;
constexpr float INV1 = 0.14433756729740643f;  // 1/sqrt(48)
constexpr float NAc  = 0.10206207261596575f;  // 1/sqrt(2*48)
constexpr float NBc  = 0.22360679774997896f;  // 1/sqrt(2*10)
constexpr float NB3  = 0.12909944487358055f;  // NBc/sqrt(3)
constexpr float C20  = 0.22360679774997896f;  // 1/sqrt(20)
constexpr float RATIO= 1.2649110640673518f;   // NB3/NAc
constexpr float DSP  = 30.0f/31.0f;
constexpr float GCOEF= -0.5f/(DSP*DSP);

typedef __attribute__((ext_vector_type(8))) short bf16x8;
typedef __attribute__((ext_vector_type(4))) float f32x4;

__device__ __forceinline__ unsigned short f2bf(float x) {
    unsigned u = __builtin_bit_cast(unsigned, x);
    u += 0x7fffu + ((u >> 16) & 1u);     // RNE
    return (unsigned short)(u >> 16);
}

// tile/lane-slot -> original W2 column (or -1 = padding lane)
__device__ __forceinline__ int colmap(int layer, int t, int lm) {
    if (layer == 0) return t*16 + lm;                           // W1 identity
    if (layer == 1) {
        if (t < 144) { const int og=t/48, i=t-og*48; return i*48 + og*16 + lm; }      // w00
        const int i = t-144; return (lm<10) ? 2304 + i*10 + lm : -1;                  // w01
    }
    if (t < 144) { const int og=t/48, i=t-og*48; return i*48 + og*16 + lm; }          // w00
    if (t < 174) { const int s=t-144, og=s/10, i=s-og*10; return 2884 + i*48 + og*16 + lm; } // w11s
    if (t < 222) { const int i=t-174; return (lm<10) ? 2304 + i*10 + lm : -1; }       // w01
    if (t < 232) { const int i=t-222; return (lm<10) ? 2784 + i*10 + lm : -1; }       // w10
    { const int i=t-232; return (lm<10) ? 3364 + i*10 + lm : -1; }                    // w11p
}

// fp32 W[144][ncol] (+bias at k=144) -> permuted bf16 B-fragments, K padded 160
__global__ __launch_bounds__(256)
void cvt_swz(const float* __restrict__ W, const float* __restrict__ bias,
             short* __restrict__ Wsw, int ncol, int ntile, int layer)
{
    const int gid = blockIdx.x*256 + threadIdx.x;
    const int g = gid >> 6, lane = gid & 63;
    if (g >= ntile*5) return;
    const int tile = g/5, ks = g - tile*5;
    const int c  = colmap(layer, tile, lane & 15);
    const int k0 = ks*32 + (lane >> 4)*8;
    union { uint4 u4; unsigned short h[8]; } pk;
    #pragma unroll
    for (int j=0;j<8;j++) {
        const int k = k0 + j;
        float v = 0.f;
        if (c >= 0) {
            if (k < 144)       v = W[(size_t)k*ncol + c];
            else if (k == 144) v = bias[c];
        }
        pk.h[j] = f2bf(v);
    }
    *(uint4*)&Wsw[((size_t)g*64 + lane)*8] = pk.u4;
}

// ----------------------------------------------------------------------------
__global__ __launch_bounds__(256)
void edge_kernel(const float* __restrict__ pos, const float* __restrict__ sigma,
                 const int* __restrict__ ei,
                 const float* __restrict__ W1, const float* __restrict__ b1,
                 const float* __restrict__ W2, const float* __restrict__ b2,
                 float* __restrict__ edge_emb, float* __restrict__ sh1buf,
                 int* __restrict__ deg, int E)
{
    __shared__ float inl[4][64];
    __shared__ float hidl[4][48];
    const int w    = threadIdx.x >> 6;
    const int lane = threadIdx.x & 63;
    const int e    = blockIdx.x*4 + w;
    const bool valid = (e < E);
    const int ec = valid ? e : 0;
    const int src = ei[ec], dst = ei[E+ec];
    const float vx = pos[dst*3+0]-pos[src*3+0];
    const float vy = pos[dst*3+1]-pos[src*3+1];
    const float vz = pos[dst*3+2]-pos[src*3+2];
    const float d  = sqrtf(vx*vx+vy*vy+vz*vz);
    const float si = SQ3f/(d+1e-8f);
    const float s0 = vx*si, s1 = vy*si, s2 = vz*si;
    if (lane < 32) {
        inl[w][lane] = sigma[src*32+lane];
    } else {
        const float off  = (float)(lane-32)*DSP;
        const float diff = d - off;
        inl[w][lane] = expf(GCOEF*diff*diff);
    }
    __syncthreads();
    if (lane < 48) {
        float a = b1[lane];
        #pragma unroll 8
        for (int j=0;j<64;j++) a = fmaf(inl[w][j], W1[j*48+lane], a);
        hidl[w][lane] = fmaxf(a, 0.f);
    }
    __syncthreads();
    if (valid) {
        if (lane < 48) {
            float a = b2[lane];
            #pragma unroll 8
            for (int j=0;j<48;j++) a = fmaf(hidl[w][j], W2[j*48+lane], a);
            edge_emb[e*48+lane] = a;
        }
        if (lane == 0) atomicAdd(&deg[dst], 1);
        if (lane < 3)  sh1buf[e*4+lane] = (lane==0)?s0:((lane==1)?s1:s2);
    }
}

// ----------------------------------------------------------------------------
__device__ __forceinline__ void load_bfrag(const short* __restrict__ Wsw,
                                           int tile, int lane, bf16x8 (&b)[5]) {
    #pragma unroll
    for (int ks=0; ks<5; ks++)
        b[ks] = *(const bf16x8*)&Wsw[((size_t)(tile*5+ks)*64 + lane)*8];
}

// one permuted region: tiles base+i, i = wv, wv+4, ... < count; upd(i, a0, a1)
template<typename F>
__device__ __forceinline__ void region(const short* __restrict__ Wsw, int base,
                                       int count, int wv, int lane,
                                       const bf16x8 (&ag)[2][5], F&& upd)
{
    bf16x8 bc[5], bn[5];
    int i = wv;
    if (i < count) load_bfrag(Wsw, base+i, lane, bc);
    for (; i < count; i += 4) {
        if (i+4 < count) load_bfrag(Wsw, base+i+4, lane, bn);
        f32x4 a0 = {0.f,0.f,0.f,0.f}, a1 = {0.f,0.f,0.f,0.f};
        #pragma unroll
        for (int ks=0; ks<5; ks++) {
            a0 = __builtin_amdgcn_mfma_f32_16x16x32_bf16(ag[0][ks], bc[ks], a0, 0,0,0);
            a1 = __builtin_amdgcn_mfma_f32_16x16x32_bf16(ag[1][ks], bc[ks], a1, 0,0,0);
        }
        upd(i, a0, a1);
        #pragma unroll
        for (int ks=0; ks<5; ks++) bc[ks] = bn[ks];
    }
}

// ----------------------------------------------------------------------------
// Fused conv layer: 32 edges/block, 4 waves. No atomics until the final
// per-node scatter (native unsafeAtomicAdd).
// ----------------------------------------------------------------------------
template<int LAYER>
__global__ __launch_bounds__(256, 2)
void conv_kernel(const float* __restrict__ edge_emb, const float* __restrict__ sh1buf,
                 const int* __restrict__ ei,
                 const float* __restrict__ sin_, const float* __restrict__ vin,
                 const short* __restrict__ W1sw, const short* __restrict__ W2sw,
                 float* __restrict__ outS, float* __restrict__ outV, int E)
{
    // pool layout (floats):
    //  stage/GEMM1:  eaB = 32*192 shorts (3072 fl)
    //  phase 1:      pacc_s[wv][e][49-pad]  = 4*1568 = 6272
    //  L1 phase 2:   pacc_vc at 6272..7552
    //  L2 phase 2 (after mid-reduce): vc at 0 (1280), v at 1280 (3840), p at 5120 (3840)
    constexpr int POOL_FL = (LAYER==1) ? 7552 : 8960;
    __shared__ __align__(16) float pool[POOL_FL];
    __shared__ __align__(16) short hidB[32*192];
    __shared__ float xsL[32*49];
    __shared__ float sh1l[32][4];
    __shared__ int   srcl[32], dstl[32];
    __shared__ float xvL[LAYER==2 ? 32*30 : 1];
    __shared__ float uL [LAYER==2 ? 32*10 : 1];
    __shared__ float cvL[LAYER==2 ? 32*30 : 1];

    short* eaB = (short*)pool;

    const int t  = threadIdx.x;
    const int eb = blockIdx.x * 32;

    if (t < 32) {
        const int ge = eb + t; const int gc = (ge < E) ? ge : (E-1);
        srcl[t] = ei[gc]; dstl[t] = ei[E+gc];
    }
    if (t < 128) {
        const int e = t >> 2, k = t & 3;
        const int ge = eb + e; const int gc = (ge<E)?ge:(E-1);
        sh1l[e][k] = sh1buf[gc*4 + k];
    }
    __syncthreads();

    // ---- stage ea -> bf16 swizzled LDS (+ fp32 copies for epilogue)
    for (int p = t; p < 32*24; p += 256) {
        const int m = p / 24, s = p - m*24;
        const int k0 = s*8;
        float vals[8] = {0.f,0.f,0.f,0.f,0.f,0.f,0.f,0.f};
        if (k0 < 48) {
            const int ge = eb + m; const int gc = (ge<E)?ge:(E-1);
            const float4 a = *(const float4*)&edge_emb[gc*48 + k0];
            const float4 b = *(const float4*)&edge_emb[gc*48 + k0 + 4];
            vals[0]=a.x; vals[1]=a.y; vals[2]=a.z; vals[3]=a.w;
            vals[4]=b.x; vals[5]=b.y; vals[6]=b.z; vals[7]=b.w;
        } else if (k0 < 96) {
            const float4 a = *(const float4*)&sin_[srcl[m]*48 + (k0-48)];
            const float4 b = *(const float4*)&sin_[srcl[m]*48 + (k0-48) + 4];
            vals[0]=a.x; vals[1]=a.y; vals[2]=a.z; vals[3]=a.w;
            vals[4]=b.x; vals[5]=b.y; vals[6]=b.z; vals[7]=b.w;
            #pragma unroll
            for (int j=0;j<8;j++) xsL[m*49 + (k0-48) + j] = vals[j];
        } else if (k0 < 144) {
            const float4 a = *(const float4*)&sin_[dstl[m]*48 + (k0-96)];
            const float4 b = *(const float4*)&sin_[dstl[m]*48 + (k0-96) + 4];
            vals[0]=a.x; vals[1]=a.y; vals[2]=a.z; vals[3]=a.w;
            vals[4]=b.x; vals[5]=b.y; vals[6]=b.z; vals[7]=b.w;
        } else if (k0 == 144) {
            vals[0] = 1.f;                       // bias row
        }
        union { uint4 u4; unsigned short h[8]; } pk;
        #pragma unroll
        for (int j=0;j<8;j++) pk.h[j] = f2bf(vals[j]);
        *(uint4*)&eaB[m*192 + ((s ^ (m&7))*8)] = pk.u4;
    }
    // hidB K-pad slots: k=144 -> 1.0 (bias row), k=145..159 -> 0
    if (t < 64) {
        const int m = t >> 1, s = 18 + (t & 1);
        union { uint4 u4; unsigned short h[8]; } pk;
        pk.u4.x = pk.u4.y = pk.u4.z = pk.u4.w = 0u;
        if (s == 18) pk.h[0] = f2bf(1.f);
        *(uint4*)&hidB[m*192 + ((s ^ (m&7))*8)] = pk.u4;
    }
    if (LAYER==2) {
        for (int p=t; p<320; p+=256) {
            const int e = p/10, i = p - e*10;
            const float* vp = &vin[srcl[e]*30 + i*3];
            const float x0=vp[0], x1=vp[1], x2=vp[2];
            const float h0=sh1l[e][0], h1=sh1l[e][1], h2=sh1l[e][2];
            xvL[e*30+i*3+0]=x0; xvL[e*30+i*3+1]=x1; xvL[e*30+i*3+2]=x2;
            uL[e*10+i] = x0*h0 + x1*h1 + x2*h2;
            cvL[e*30+i*3+0] = x1*h2 - x2*h1;
            cvL[e*30+i*3+1] = x2*h0 - x0*h2;
            cvL[e*30+i*3+2] = x0*h1 - x1*h0;
        }
    }
    __syncthreads();

    const int wv = t >> 6, lane = t & 63;
    const int lm = lane & 15, lk = lane >> 4;
    const int lk4 = lk*4;

    // ---- GEMM1: hid = relu(ea @ W1) (bias via K-row), -> swizzled bf16 LDS
    {
        bf16x8 af[2][5];
        #pragma unroll
        for (int mt=0; mt<2; mt++) {
            const int m = mt*16 + lm;
            #pragma unroll
            for (int ks=0; ks<5; ks++)
                af[mt][ks] = *(const bf16x8*)&eaB[m*192 + (((ks*4+lk) ^ (m&7))*8)];
        }
        for (int nt = wv; nt < 9; nt += 4) {
            bf16x8 bf_[5];
            load_bfrag(W1sw, nt, lane, bf_);
            f32x4 a0 = {0.f,0.f,0.f,0.f}, a1 = {0.f,0.f,0.f,0.f};
            #pragma unroll
            for (int ks=0; ks<5; ks++) {
                a0 = __builtin_amdgcn_mfma_f32_16x16x32_bf16(af[0][ks], bf_[ks], a0, 0,0,0);
                a1 = __builtin_amdgcn_mfma_f32_16x16x32_bf16(af[1][ks], bf_[ks], a1, 0,0,0);
            }
            const int c = nt*16 + lm;
            #pragma unroll
            for (int r=0; r<4; r++) {
                const int m0 = lk4 + r, m1 = 16 + lk4 + r;
                hidB[m0*192 + (((c>>3) ^ (m0&7))*8) + (c&7)] = (short)f2bf(fmaxf(a0[r], 0.f));
                hidB[m1*192 + (((c>>3) ^ (m1&7))*8) + (c&7)] = (short)f2bf(fmaxf(a1[r], 0.f));
            }
        }
    }
    __syncthreads();   // eaB dead from here; pool reusable

    bf16x8 ag[2][5];
    #pragma unroll
    for (int mt=0; mt<2; mt++) {
        const int m = mt*16 + lm;
        #pragma unroll
        for (int ks=0; ks<5; ks++)
            ag[mt][ks] = *(const bf16x8*)&hidB[m*192 + (((ks*4+lk) ^ (m&7))*8)];
    }

    // ---- phase 1: m_s  (w00 [+ w11s for layer 2]) — register accumulation
    for (int og=0; og<3; og++) {
        float ms[2][4] = {{0.f,0.f,0.f,0.f},{0.f,0.f,0.f,0.f}};
        region(W2sw, og*48, 48, wv, lane, ag, [&](int i, f32x4 a0, f32x4 a1) {
            #pragma unroll
            for (int r=0; r<4; r++) {
                ms[0][r] = fmaf(a0[r], xsL[(lk4+r)*49 + i],      ms[0][r]);
                ms[1][r] = fmaf(a1[r], xsL[(16+lk4+r)*49 + i],   ms[1][r]);
            }
        });
        if (LAYER==2) {
            region(W2sw, 144+og*10, 10, wv, lane, ag, [&](int i, f32x4 a0, f32x4 a1) {
                #pragma unroll
                for (int r=0; r<4; r++) {
                    ms[0][r] = fmaf(a0[r]*RATIO, uL[(lk4+r)*10 + i],    ms[0][r]);
                    ms[1][r] = fmaf(a1[r]*RATIO, uL[(16+lk4+r)*10 + i], ms[1][r]);
                }
            });
        }
        #pragma unroll
        for (int r=0; r<4; r++) {
            pool[wv*1568 + (lk4+r)*49    + og*16+lm] = ms[0][r];
            pool[wv*1568 + (16+lk4+r)*49 + og*16+lm] = ms[1][r];
        }
    }

    if (LAYER==1) {
        // ---- phase 2: w01 -> pacc_vc at 6272
        float mv[2][4] = {{0.f,0.f,0.f,0.f},{0.f,0.f,0.f,0.f}};
        region(W2sw, 144, 48, wv, lane, ag, [&](int i, f32x4 a0, f32x4 a1) {
            #pragma unroll
            for (int r=0; r<4; r++) {
                mv[0][r] = fmaf(a0[r], xsL[(lk4+r)*49 + i],    mv[0][r]);
                mv[1][r] = fmaf(a1[r], xsL[(16+lk4+r)*49 + i], mv[1][r]);
            }
        });
        if (lm < 10) {
            #pragma unroll
            for (int r=0; r<4; r++) {
                pool[6272 + wv*320 + (lk4+r)*10    + lm] = mv[0][r];
                pool[6272 + wv*320 + (16+lk4+r)*10 + lm] = mv[1][r];
            }
        }
        __syncthreads();
        // ---- reduce + scatter
        for (int p=t; p<1536; p+=256) {
            const int e = p/48, o = p - (p/48)*48;
            if (eb+e < E) {
                const int a = e*49 + o;
                const float v = pool[a] + pool[1568+a] + pool[3136+a] + pool[4704+a];
                unsafeAtomicAdd(&outS[dstl[e]*48 + o], v*INV1);
            }
        }
        for (int p=t; p<320; p+=256) {
            const int e = p/10, o = p - (p/10)*10;
            if (eb+e < E) {
                const int a = 6272 + e*10 + o;
                float v = pool[a] + pool[a+320] + pool[a+640] + pool[a+960];
                v *= INV1;
                #pragma unroll
                for (int d=0; d<3; d++)
                    unsafeAtomicAdd(&outV[dstl[e]*30 + o*3 + d], v*sh1l[e][d]);
            }
        }
    } else {
        __syncthreads();
        // ---- mid-reduce m_s, then reuse pool for phase 2
        for (int p=t; p<1536; p+=256) {
            const int e = p/48, o = p - (p/48)*48;
            if (eb+e < E) {
                const int a = e*49 + o;
                const float v = pool[a] + pool[1568+a] + pool[3136+a] + pool[4704+a];
                unsafeAtomicAdd(&outS[dstl[e]*108 + o], v*NAc);
            }
        }
        __syncthreads();

        // ---- phase 2: w01 -> vc(0), w10 -> v(1280), w11p -> p(5120)
        {
            float mv[2][4] = {{0.f,0.f,0.f,0.f},{0.f,0.f,0.f,0.f}};
            region(W2sw, 174, 48, wv, lane, ag, [&](int i, f32x4 a0, f32x4 a1) {
                #pragma unroll
                for (int r=0; r<4; r++) {
                    mv[0][r] = fmaf(a0[r], xsL[(lk4+r)*49 + i],    mv[0][r]);
                    mv[1][r] = fmaf(a1[r], xsL[(16+lk4+r)*49 + i], mv[1][r]);
                }
            });
            if (lm < 10) {
                #pragma unroll
                for (int r=0; r<4; r++) {
                    pool[wv*320 + (lk4+r)*10    + lm] = mv[0][r];
                    pool[wv*320 + (16+lk4+r)*10 + lm] = mv[1][r];
                }
            }
        }
        {
            float m3[2][4][3] = {};
            region(W2sw, 222, 10, wv, lane, ag, [&](int i, f32x4 a0, f32x4 a1) {
                #pragma unroll
                for (int r=0; r<4; r++)
                    #pragma unroll
                    for (int d=0; d<3; d++) {
                        m3[0][r][d] = fmaf(a0[r], xvL[(lk4+r)*30 + i*3 + d],    m3[0][r][d]);
                        m3[1][r][d] = fmaf(a1[r], xvL[(16+lk4+r)*30 + i*3 + d], m3[1][r][d]);
                    }
            });
            if (lm < 10) {
                #pragma unroll
                for (int r=0; r<4; r++)
                    #pragma unroll
                    for (int d=0; d<3; d++) {
                        pool[1280 + wv*960 + (lk4+r)*30    + lm*3 + d] = m3[0][r][d];
                        pool[1280 + wv*960 + (16+lk4+r)*30 + lm*3 + d] = m3[1][r][d];
                    }
            }
        }
        {
            float m3[2][4][3] = {};
            region(W2sw, 232, 10, wv, lane, ag, [&](int i, f32x4 a0, f32x4 a1) {
                #pragma unroll
                for (int r=0; r<4; r++)
                    #pragma unroll
                    for (int d=0; d<3; d++) {
                        m3[0][r][d] = fmaf(a0[r], cvL[(lk4+r)*30 + i*3 + d],    m3[0][r][d]);
                        m3[1][r][d] = fmaf(a1[r], cvL[(16+lk4+r)*30 + i*3 + d], m3[1][r][d]);
                    }
            });
            if (lm < 10) {
                #pragma unroll
                for (int r=0; r<4; r++)
                    #pragma unroll
                    for (int d=0; d<3; d++) {
                        pool[5120 + wv*960 + (lk4+r)*30    + lm*3 + d] = m3[0][r][d];
                        pool[5120 + wv*960 + (16+lk4+r)*30 + lm*3 + d] = m3[1][r][d];
                    }
            }
        }
        __syncthreads();
        // ---- reduce + scatter (vector parts)
        for (int p=t; p<320; p+=256) {
            const int e = p/10, o = p - (p/10)*10;
            if (eb+e < E) {
                const int a = e*10 + o;
                const float vc = pool[a] + pool[a+320] + pool[a+640] + pool[a+960];
                const int base = dstl[e]*108;
                #pragma unroll
                for (int d=0; d<3; d++) {
                    const int b = e*30 + o*3 + d;
                    const float vv = pool[1280+b] + pool[1280+960+b] + pool[1280+1920+b] + pool[1280+2880+b];
                    const float pp = pool[5120+b] + pool[5120+960+b] + pool[5120+1920+b] + pool[5120+2880+b];
                    unsafeAtomicAdd(&outS[base + 48 + o*3 + d], vc*NAc*sh1l[e][d] + vv*NBc);
                    unsafeAtomicAdd(&outS[base + 78 + o*3 + d], pp*C20);
                }
            }
        }
    }
}

// ----------------------------------------------------------------------------
__global__ __launch_bounds__(256)
void fin1_kernel(const float* __restrict__ node_s, const int* __restrict__ deg,
                 float* __restrict__ s1, float* __restrict__ v1, int Nn)
{
    const int p = blockIdx.x*256 + threadIdx.x;
    const int totS = Nn*48;
    if (p < totS) {
        const int n = p/48;
        const int dgi = deg[n];
        const float dg = (float)(dgi > 1 ? dgi : 1);
        s1[p] = node_s[p] + s1[p]/dg;
    } else {
        const int q = p - totS;
        if (q < Nn*30) {
            const int n = q/30;
            const int dgi = deg[n];
            const float dg = (float)(dgi > 1 ? dgi : 1);
            v1[q] = v1[q]/dg;
        }
    }
}

__global__ __launch_bounds__(256)
void fin2_kernel(const float* __restrict__ s1, const float* __restrict__ v1,
                 const int* __restrict__ deg, float* __restrict__ out, int Nn)
{
    const int p = blockIdx.x*256 + threadIdx.x;
    if (p >= Nn*108) return;
    const int n = p/108, c = p - n*108;
    const int dgi = deg[n];
    const float dg = (float)(dgi > 1 ? dgi : 1);
    const float acc = out[p]/dg;
    if (c < 48)      out[p] = s1[n*48+c] + acc;
    else if (c < 78) out[p] = v1[n*30 + (c-48)] + acc;
    else             out[p] = acc;
}

// ----------------------------------------------------------------------------
extern "C" void kernel_launch(void* const* d_in, const int* in_sizes, int n_in,
                              void* d_out, int out_size, void* d_ws, size_t ws_size,
                              hipStream_t stream)
{
    const float* pos    = (const float*)d_in[0];
    const float* sigma  = (const float*)d_in[1];
    const float* node_s = (const float*)d_in[2];
    const float* eW1  = (const float*)d_in[3];
    const float* eb1  = (const float*)d_in[4];
    const float* eW2  = (const float*)d_in[5];
    const float* eb2  = (const float*)d_in[6];
    const float* f1W1 = (const float*)d_in[7];
    const float* f1b1 = (const float*)d_in[8];
    const float* f1W2 = (const float*)d_in[9];
    const float* f1b2 = (const float*)d_in[10];
    const float* f2W1 = (const float*)d_in[11];
    const float* f2b1 = (const float*)d_in[12];
    const float* f2W2 = (const float*)d_in[13];
    const float* f2b2 = (const float*)d_in[14];
    const int*   ei   = (const int*)d_in[15];
    const int Nn = in_sizes[0]/3;
    const int E  = in_sizes[15]/2;
    float* out = (float*)d_out;

    char* ws = (char*)d_ws;
    float* edge_emb = (float*)ws;  ws += (size_t)E*48*sizeof(float);
    float* sh1buf   = (float*)ws;  ws += (size_t)E*4*sizeof(float);
    float* s1       = (float*)ws;  ws += (size_t)Nn*48*sizeof(float);
    float* v1       = (float*)ws;  ws += (size_t)Nn*30*sizeof(float);
    int*   deg      = (int*)ws;    ws += (size_t)Nn*sizeof(int);
    short* W1sw     = (short*)ws;  ws += (size_t)9*5*64*8*sizeof(short);
    short* W2sw     = (short*)ws;  ws += (size_t)242*5*64*8*sizeof(short);

    hipMemsetAsync(s1,  0, (size_t)Nn*48*sizeof(float), stream);
    hipMemsetAsync(v1,  0, (size_t)Nn*30*sizeof(float), stream);
    hipMemsetAsync(deg, 0, (size_t)Nn*sizeof(int),      stream);
    hipMemsetAsync(out, 0, (size_t)Nn*108*sizeof(float), stream);

    edge_kernel<<<(E+3)/4, 256, 0, stream>>>(pos, sigma, ei, eW1, eb1, eW2, eb2,
                                             edge_emb, sh1buf, deg, E);

    cvt_swz<<<(9*5*64+255)/256,   256, 0, stream>>>(f1W1, f1b1, W1sw, 144, 9, 0);
    cvt_swz<<<(192*5*64+255)/256, 256, 0, stream>>>(f1W2, f1b2, W2sw, 2784, 192, 1);

    conv_kernel<1><<<(E+31)/32, 256, 0, stream>>>(edge_emb, sh1buf, ei, node_s, nullptr,
                                                  W1sw, W2sw, s1, v1, E);
    fin1_kernel<<<((size_t)Nn*78 + 255)/256, 256, 0, stream>>>(node_s, deg, s1, v1, Nn);

    cvt_swz<<<(9*5*64+255)/256,   256, 0, stream>>>(f2W1, f2b1, W1sw, 144, 9, 0);
    cvt_swz<<<(242*5*64+255)/256, 256, 0, stream>>>(f2W2, f2b2, W2sw, 3464, 242, 2);

    conv_kernel<2><<<(E+31)/32, 256, 0, stream>>>(edge_emb, sh1buf, ei, s1, v1,
                                                  W1sw, W2sw, out, nullptr, E);
    fin2_kernel<<<((size_t)Nn*108 + 255)/256, 256, 0, stream>>>(s1, v1, deg, out, Nn);
}